// Round 19
// baseline (150.249 us; speedup 1.0000x reference)
//
#include <hip/hip_runtime.h>
#include <hip/hip_fp16.h>

#define D_IN  128
#define D_HID 128
#define D_OUT 64
#define NBMAX 512      // max buckets (N <= 65536; packed formats assume this)
#define CHUNK 1024     // edges per k_bucket block (halved: +TLP for latency-bound sort)
#define EPB   4        // edges per thread in bucket body (CHUNK/256)
#define FCACHE 3072    // k_fin LDS edge cache (bucket mean ~2046, max ~2300)

typedef __attribute__((ext_vector_type(8))) short bf16x8;
typedef __attribute__((ext_vector_type(4))) float f32x4;

__device__ __forceinline__ unsigned short f2bf_rne(float f) {
    unsigned int u = __float_as_uint(f);
    return (unsigned short)((u + 0x7FFFu + ((u >> 16) & 1u)) >> 16);
}

// ---------------------------------------------------------------- prep:
// split W1/W2 to transposed hi/lo bf16 (B-frag-ready [j][k]) + zero counters.
__launch_bounds__(256)
__global__ void k_prep(const float* __restrict__ W1, const float* __restrict__ W2,
                       unsigned short* __restrict__ W1h, unsigned short* __restrict__ W1l,
                       unsigned short* __restrict__ W2h, unsigned short* __restrict__ W2l,
                       int* __restrict__ cntD, int* __restrict__ cntS, int NB) {
    const int b = blockIdx.x, t = threadIdx.x;
    if (b < 64) {                       // W1: 128x128
        const int i = b * 256 + t;      // i = k*128 + j
        const int k = i >> 7, j = i & 127;
        const float v = W1[i];
        const unsigned short hb = f2bf_rne(v);
        const float hf = __uint_as_float((unsigned int)hb << 16);
        W1h[j * 128 + k] = hb;
        W1l[j * 128 + k] = f2bf_rne(v - hf);
    } else if (b < 96) {                // W2: 128x64
        const int i = (b - 64) * 256 + t;   // i = k*64 + j
        const int k = i >> 6, j = i & 63;
        const float v = W2[i];
        const unsigned short hb = f2bf_rne(v);
        const float hf = __uint_as_float((unsigned int)hb << 16);
        W2h[j * 128 + k] = hb;
        W2l[j * 128 + k] = f2bf_rne(v - hf);
    } else {
        for (int i = t; i < NB; i += 256) { cntD[i] = 0; cntS[i] = 0; }
    }
}

// ---------------------------------------------------------------- merged bucket + gemm1 LDS
struct BucketS {
    int lc[512], ls[512];
    int baD[512], baS[512];
    int gbD[512], gbS[512];
    int wsumD[4], wsumS[4];
    unsigned int  ldsD[CHUNK];
    int           gposD[CHUNK];
    unsigned char ldsS[CHUNK];
    int           gposS[CHUNK];
};
struct GemmS {
    short Ah[32][136];
    short Al[32][136];
};
union SMem { BucketS b; GemmS g; };

// ---- bucket body: counting-sort pass 1, wave-level scans (2 barriers);
// BOTH sides LDS-staged then flushed (write-combining > occupancy — r17 lesson).
__device__ __forceinline__ void bucket_body(
        BucketS& sm, int bx,
        const int* __restrict__ src, const int* __restrict__ dst,
        int E, int NB, int cap,
        int* __restrict__ cntD, int* __restrict__ cntS,
        unsigned int* __restrict__ storeD, unsigned char* __restrict__ storeS) {
    const int t = threadIdx.x;
    const int e0 = bx * CHUNK;
    const int e1 = min(e0 + CHUNK, E);
    const int n  = e1 - e0;

    int sv[EPB], dv[EPB];
#pragma unroll
    for (int u = 0; u < EPB; ++u) {
        const int i = e0 + u * 256 + t;
        if (i < e1) { sv[u] = src[i]; dv[u] = dst[i]; }
        else        { sv[u] = -1;     dv[u] = -1; }
    }

    sm.lc[t] = 0; sm.lc[t + 256] = 0; sm.ls[t] = 0; sm.ls[t + 256] = 0;
    __syncthreads();
#pragma unroll
    for (int u = 0; u < EPB; ++u) {
        if (sv[u] >= 0) {
            atomicAdd(&sm.lc[dv[u] >> 7], 1);
            atomicAdd(&sm.ls[sv[u] >> 7], 1);
        }
    }
    __syncthreads();

    // exclusive scans over 512 bins (thread t owns bins 2t, 2t+1):
    // per-wave shfl scan + cross-wave fixup (2 barriers total)
    const int c0 = sm.lc[2 * t], c1 = sm.lc[2 * t + 1];
    const int s0 = sm.ls[2 * t], s1 = sm.ls[2 * t + 1];
    const int pc = c0 + c1, ps = s0 + s1;
    const int wl = t & 63, wv = t >> 6;
    int incD = pc, incS = ps;
#pragma unroll
    for (int off = 1; off < 64; off <<= 1) {
        const int oD = __shfl_up(incD, off);
        const int oS = __shfl_up(incS, off);
        if (wl >= off) { incD += oD; incS += oS; }
    }
    if (wl == 63) { sm.wsumD[wv] = incD; sm.wsumS[wv] = incS; }
    __syncthreads();
    int baseD = 0, baseS = 0;
#pragma unroll
    for (int ww = 0; ww < 4; ++ww) {
        if (ww < wv) { baseD += sm.wsumD[ww]; baseS += sm.wsumS[ww]; }
    }
    const int exD = baseD + incD - pc;
    const int exS = baseS + incS - ps;
    sm.baD[2 * t] = exD; sm.baD[2 * t + 1] = exD + c0;
    sm.baS[2 * t] = exS; sm.baS[2 * t + 1] = exS + s0;
    __syncthreads();

    for (int i = t; i < NB; i += 256) {
        const int c = sm.lc[i];
        sm.gbD[i] = i * cap + (c ? atomicAdd(&cntD[i], c) : 0);
        const int s = sm.ls[i];
        sm.gbS[i] = i * cap + (s ? atomicAdd(&cntS[i], s) : 0);
    }
    __syncthreads();
    sm.lc[t] = 0; sm.lc[t + 256] = 0; sm.ls[t] = 0; sm.ls[t + 256] = 0;
    __syncthreads();

#pragma unroll
    for (int u = 0; u < EPB; ++u) {
        if (sv[u] >= 0) {
            const int s = sv[u], d = dv[u];
            const int bd = d >> 7;
            const int lp = atomicAdd(&sm.lc[bd], 1);
            const int p  = sm.baD[bd] + lp;
            sm.ldsD[p]  = (unsigned int)s | ((unsigned int)(d & 127) << 16);
            sm.gposD[p] = sm.gbD[bd] + lp;
            const int bs = s >> 7;
            const int lq = atomicAdd(&sm.ls[bs], 1);
            const int q  = sm.baS[bs] + lq;
            sm.ldsS[q]  = (unsigned char)(s & 127);
            sm.gposS[q] = sm.gbS[bs] + lq;
        }
    }
    __syncthreads();

    for (int p = t; p < n; p += 256) {
        storeD[sm.gposD[p]] = sm.ldsD[p];
        storeS[sm.gposS[p]] = sm.ldsS[p];
    }
}

// ---- gemm1 body: Y1 = (half)(X @ W1), X fp32, unscaled (scale moved to gather)
__device__ __forceinline__ void gemm1_body(
        GemmS& sm, int bx,
        const float* __restrict__ X,
        const unsigned short* __restrict__ Wth, const unsigned short* __restrict__ Wtl,
        __half* __restrict__ Y, int N) {
    const int t = threadIdx.x;
    const int row0 = bx * 32;

#pragma unroll
    for (int p = 0; p < 4; ++p) {
        const int idx = p * 256 + t;          // float4 units
        const int r   = idx >> 5;
        const int c4  = (idx & 31) << 2;
        const int gr  = row0 + r;
        float4 v = make_float4(0.f, 0.f, 0.f, 0.f);
        if (gr < N) v = *(const float4*)(X + (long long)gr * 128 + c4);
        const float f[4] = {v.x, v.y, v.z, v.w};
        short hh[4], ll[4];
#pragma unroll
        for (int i = 0; i < 4; ++i) {
            const unsigned short hb = f2bf_rne(f[i]);
            const float hf = __uint_as_float(((unsigned int)hb) << 16);
            hh[i] = (short)hb;
            ll[i] = (short)f2bf_rne(f[i] - hf);
        }
        *(short4*)&sm.Ah[r][c4] = make_short4(hh[0], hh[1], hh[2], hh[3]);
        *(short4*)&sm.Al[r][c4] = make_short4(ll[0], ll[1], ll[2], ll[3]);
    }
    __syncthreads();

    constexpr int NT = 4;                     // 128 cols / 32
    const int w    = t >> 6;
    const int lane = t & 63;
    const int rg = w & 1, cg = w >> 1;
    const int lrow = lane & 15;
    const int lk   = (lane >> 4) << 3;
    const int colbase = cg * (16 * NT);

    f32x4 acc[NT];
#pragma unroll
    for (int n = 0; n < NT; ++n) acc[n] = (f32x4){0.f, 0.f, 0.f, 0.f};

#pragma unroll
    for (int ks = 0; ks < 4; ++ks) {
        const int k = ks * 32 + lk;
        const bf16x8 ah = *(const bf16x8*)&sm.Ah[rg * 16 + lrow][k];
        const bf16x8 al = *(const bf16x8*)&sm.Al[rg * 16 + lrow][k];
#pragma unroll
        for (int n = 0; n < NT; ++n) {
            const int col = colbase + n * 16 + lrow;
            const bf16x8 bh = *(const bf16x8*)(Wth + (size_t)col * 128 + k);
            const bf16x8 bl = *(const bf16x8*)(Wtl + (size_t)col * 128 + k);
            acc[n] = __builtin_amdgcn_mfma_f32_16x16x32_bf16(ah, bh, acc[n], 0, 0, 0);
            acc[n] = __builtin_amdgcn_mfma_f32_16x16x32_bf16(ah, bl, acc[n], 0, 0, 0);
            acc[n] = __builtin_amdgcn_mfma_f32_16x16x32_bf16(al, bh, acc[n], 0, 0, 0);
        }
    }

#pragma unroll
    for (int n = 0; n < NT; ++n) {
#pragma unroll
        for (int i = 0; i < 4; ++i) {
            const int r = row0 + rg * 16 + ((lane >> 4) << 2) + i;
            if (r < N)
                Y[(long long)r * D_HID + colbase + n * 16 + lrow] = __float2half(acc[n][i]);
        }
    }
}

// ---- merged dispatch: blocks [0, nbBlk) sort; [nbBlk, nbBlk+gemmBlk) gemm1
__launch_bounds__(256)
__global__ void k_bucket_gemm(const int* __restrict__ src, const int* __restrict__ dst,
                              int E, int NB, int cap,
                              int* __restrict__ cntD, int* __restrict__ cntS,
                              unsigned int* __restrict__ storeD, unsigned char* __restrict__ storeS,
                              const float* __restrict__ X,
                              const unsigned short* __restrict__ Wth,
                              const unsigned short* __restrict__ Wtl,
                              __half* __restrict__ Y, int N, int nbBlk) {
    __shared__ SMem sm;
    const int bx = (int)blockIdx.x;
    if (bx < nbBlk)
        bucket_body(sm.b, bx, src, dst, E, NB, cap, cntD, cntS, storeD, storeS);
    else
        gemm1_body(sm.g, bx - nbBlk, X, Wth, Wtl, Y, N);
}

// ---------------------------------------------------------------- finalize (scan fused)
// Grid = 2*NB: blocks [0,NB) do the dst side (rowptr/inv_in/csr_src);
// blocks [NB,2NB) do the src side (inv_out). Independent -> 2x parallelism.
__launch_bounds__(256)
__global__ void k_fin(const unsigned int* __restrict__ storeD, const unsigned char* __restrict__ storeS,
                      const int* __restrict__ cntD, const int* __restrict__ cntS,
                      int cap, int N, int NB, int E,
                      int* __restrict__ rowptr, float* __restrict__ inv_in,
                      float* __restrict__ inv_out, unsigned short* __restrict__ csr_src) {
    __shared__ int fh[128];
    __shared__ int sc[128];
    __shared__ int cur[128];
    __shared__ int red[256];
    __shared__ unsigned int ecache[FCACHE];
    const int t = threadIdx.x;

    if ((int)blockIdx.x >= NB) {
        // ---- src side: inv_out
        const int b = (int)blockIdx.x - NB;
        const long long sb = (long long)b * cap;
        if (t < 128) fh[t] = 0;
        __syncthreads();
        const int cnts = cntS[b];
        for (int i = t; i < cnts; i += 256) atomicAdd(&fh[storeS[sb + i]], 1);
        __syncthreads();
        if (t < 128) {
            const int node = (b << 7) + t;
            if (node < N) inv_out[node] = rsqrtf((float)max(fh[t], 1));
        }
        return;
    }

    const int b = (int)blockIdx.x;
    const long long sb = (long long)b * cap;

    int partial = 0;
    for (int i = t; i < b; i += 256) partial += cntD[i];
    red[t] = partial;
    __syncthreads();
    for (int off = 128; off > 0; off >>= 1) {
        if (t < off) red[t] += red[t + off];
        __syncthreads();
    }
    const int base = red[0];

    const int cnt = cntD[b];
    const bool cached = (cnt <= FCACHE);
    if (cached) {
        for (int i = t; i < cnt; i += 256) ecache[i] = storeD[sb + i];
    }

    if (t < 128) fh[t] = 0;
    __syncthreads();
    for (int i = t; i < cnt; i += 256) {
        const unsigned int e = cached ? ecache[i] : storeD[sb + i];
        atomicAdd(&fh[e >> 16], 1);
    }
    __syncthreads();
    if (t < 128) sc[t] = fh[t];
    __syncthreads();
    int inc = (t < 128) ? sc[t] : 0;
    for (int off = 1; off < 128; off <<= 1) {
        int o = (t >= off && t < 128) ? sc[t - off] : 0;
        __syncthreads();
        if (t < 128) { inc += o; sc[t] = inc; }
        __syncthreads();
    }
    if (t < 128) {
        const int excl = inc - fh[t];
        cur[t] = excl;
        const int node = (b << 7) + t;
        if (node < N) {
            rowptr[node] = base + excl;
            inv_in[node] = rsqrtf((float)max(fh[t], 1));
        }
    }
    if (b == NB - 1 && t == 128) rowptr[N] = E;
    __syncthreads();
    for (int i = t; i < cnt; i += 256) {
        const unsigned int e = cached ? ecache[i] : storeD[sb + i];
        const int pos = atomicAdd(&cur[e >> 16], 1);
        csr_src[base + pos] = (unsigned short)(e & 0xFFFFu);
    }
}

// ---------------------------------------------------------------- MFMA GEMM (layer 2)
template<int LDN>
__launch_bounds__(256)
__global__ void k_gemm_mfma(const __half* __restrict__ X,
                            const unsigned short* __restrict__ Wth,
                            const unsigned short* __restrict__ Wtl,
                            __half* __restrict__ Y, int N) {
    __shared__ short Ah[32][136], Al[32][136];

    const int t = threadIdx.x;
    const int row0 = blockIdx.x * 32;

#pragma unroll
    for (int p = 0; p < 2; ++p) {
        const int idx = p * 256 + t;          // half8 units
        const int r   = idx >> 4;
        const int c8  = (idx & 15) << 3;
        const int gr  = row0 + r;
        uint4 raw = make_uint4(0u, 0u, 0u, 0u);
        if (gr < N) raw = *(const uint4*)(X + (long long)gr * 128 + c8);
        const __half2* hp = (const __half2*)&raw;
        short hh[8], ll[8];
#pragma unroll
        for (int u = 0; u < 4; ++u) {
            const float2 f2 = __half22float2(hp[u]);
            const float f[2] = {f2.x, f2.y};
#pragma unroll
            for (int q = 0; q < 2; ++q) {
                const unsigned short hb = f2bf_rne(f[q]);
                const float hf = __uint_as_float(((unsigned int)hb) << 16);
                hh[2 * u + q] = (short)hb;
                ll[2 * u + q] = (short)f2bf_rne(f[q] - hf);
            }
        }
        *(short4*)&Ah[r][c8]     = make_short4(hh[0], hh[1], hh[2], hh[3]);
        *(short4*)&Ah[r][c8 + 4] = make_short4(hh[4], hh[5], hh[6], hh[7]);
        *(short4*)&Al[r][c8]     = make_short4(ll[0], ll[1], ll[2], ll[3]);
        *(short4*)&Al[r][c8 + 4] = make_short4(ll[4], ll[5], ll[6], ll[7]);
    }
    __syncthreads();

    constexpr int NT = LDN / 32;
    const int w    = t >> 6;
    const int lane = t & 63;
    const int rg = w & 1, cg = w >> 1;
    const int lrow = lane & 15;
    const int lk   = (lane >> 4) << 3;
    const int colbase = cg * (16 * NT);

    f32x4 acc[NT];
#pragma unroll
    for (int n = 0; n < NT; ++n) acc[n] = (f32x4){0.f, 0.f, 0.f, 0.f};

#pragma unroll
    for (int ks = 0; ks < 4; ++ks) {
        const int k = ks * 32 + lk;
        const bf16x8 ah = *(const bf16x8*)&Ah[rg * 16 + lrow][k];
        const bf16x8 al = *(const bf16x8*)&Al[rg * 16 + lrow][k];
#pragma unroll
        for (int n = 0; n < NT; ++n) {
            const int col = colbase + n * 16 + lrow;
            const bf16x8 bh = *(const bf16x8*)(Wth + (size_t)col * 128 + k);
            const bf16x8 bl = *(const bf16x8*)(Wtl + (size_t)col * 128 + k);
            acc[n] = __builtin_amdgcn_mfma_f32_16x16x32_bf16(ah, bh, acc[n], 0, 0, 0);
            acc[n] = __builtin_amdgcn_mfma_f32_16x16x32_bf16(ah, bl, acc[n], 0, 0, 0);
            acc[n] = __builtin_amdgcn_mfma_f32_16x16x32_bf16(al, bh, acc[n], 0, 0, 0);
        }
    }

#pragma unroll
    for (int n = 0; n < NT; ++n) {
#pragma unroll
        for (int i = 0; i < 4; ++i) {
            const int r = row0 + rg * 16 + ((lane >> 4) << 2) + i;
            if (r < N)
                Y[(long long)r * LDN + colbase + n * 16 + lrow] = __float2half(acc[n][i]);
        }
    }
}

// ---------------------------------------------------------------- CSR gather (fp16 rows, fp32 accum)
// One wave per destination node; 8 halves (16B) per lane; 8-deep MLP unroll.
// SRCSCALE: multiply each source row by inv_src[s] (moves the x*inv_out
// pre-scale of layer 1 into the gather, per-edge).
template<int D, bool RELU, bool SRCSCALE, typename TO>
__launch_bounds__(256)
__global__ void k_gather(const int* __restrict__ rowptr, const unsigned short* __restrict__ csr_src,
                         const __half* __restrict__ Y, const float* __restrict__ inv_in,
                         const float* __restrict__ inv_out, const float* __restrict__ b,
                         TO* __restrict__ out, int N, const float* __restrict__ inv_src) {
    const int wid  = (int)((blockIdx.x * 256u + threadIdx.x) >> 6);
    const int lane = threadIdx.x & 63;
    if (wid >= N) return;

    const int start = rowptr[wid];
    const int end   = rowptr[wid + 1];

    constexpr int LPE = D / 8;            // lanes per edge (16 or 8)
    constexpr int EPW = 64 / LPE;         // edges per group (4 or 8)
    const int grp  = lane / LPE;
    const int colh = (lane % LPE) * 8;

    float a[8];
#pragma unroll
    for (int u = 0; u < 8; ++u) a[u] = 0.0f;

    auto accum = [&](uint4 raw, float io) {
        const __half2* h = (const __half2*)&raw;
#pragma unroll
        for (int u = 0; u < 4; ++u) {
            const float2 f = __half22float2(h[u]);
            if constexpr (SRCSCALE) {
                a[2 * u]     += f.x * io;
                a[2 * u + 1] += f.y * io;
            } else {
                a[2 * u]     += f.x;
                a[2 * u + 1] += f.y;
            }
        }
    };

    for (int k = start; k < end; k += 64) {
        const int idx = k + lane;
        const int sv  = (idx < end) ? (int)csr_src[idx] : 0;
        const int cnt = min(64, end - k);
        int j = 0;
        for (; j + 8 * EPW <= cnt; j += 8 * EPW) {
            int s[8];
#pragma unroll
            for (int u = 0; u < 8; ++u) s[u] = __shfl(sv, j + u * EPW + grp);
            uint4 r[8];
#pragma unroll
            for (int u = 0; u < 8; ++u) r[u] = *(const uint4*)(Y + (long long)s[u] * D + colh);
            float io[8];
            if constexpr (SRCSCALE) {
#pragma unroll
                for (int u = 0; u < 8; ++u) io[u] = inv_src[s[u]];
            }
#pragma unroll
            for (int u = 0; u < 8; ++u) accum(r[u], SRCSCALE ? io[u] : 0.0f);
        }
        for (; j + 4 * EPW <= cnt; j += 4 * EPW) {
            int s[4];
#pragma unroll
            for (int u = 0; u < 4; ++u) s[u] = __shfl(sv, j + u * EPW + grp);
            uint4 r[4];
#pragma unroll
            for (int u = 0; u < 4; ++u) r[u] = *(const uint4*)(Y + (long long)s[u] * D + colh);
            float io[4];
            if constexpr (SRCSCALE) {
#pragma unroll
                for (int u = 0; u < 4; ++u) io[u] = inv_src[s[u]];
            }
#pragma unroll
            for (int u = 0; u < 4; ++u) accum(r[u], SRCSCALE ? io[u] : 0.0f);
        }
        for (; j < cnt; j += EPW) {
            const int jj = j + grp;
            const int s  = __shfl(sv, jj);   // unconditional pull (CDNA divergent-shfl rule)
            if (jj < cnt) {
                const uint4 r = *(const uint4*)(Y + (long long)s * D + colh);
                accum(r, SRCSCALE ? inv_src[s] : 0.0f);
            }
        }
    }

#pragma unroll
    for (int u = 0; u < 8; ++u) a[u] += __shfl_down(a[u], 32);
#pragma unroll
    for (int u = 0; u < 8; ++u) a[u] += __shfl_down(a[u], 16);
    if (EPW == 8) {
#pragma unroll
        for (int u = 0; u < 8; ++u) a[u] += __shfl_down(a[u], 8);
    }

    if (lane < LPE) {
        const float ii = inv_in[wid];
        const float io = RELU ? inv_out[wid] : 0.0f;
        const float4 b0 = *(const float4*)(b + colh);
        const float4 b1 = *(const float4*)(b + colh + 4);
        float r[8];
        r[0] = a[0] * ii + b0.x; r[1] = a[1] * ii + b0.y;
        r[2] = a[2] * ii + b0.z; r[3] = a[3] * ii + b0.w;
        r[4] = a[4] * ii + b1.x; r[5] = a[5] * ii + b1.y;
        r[6] = a[6] * ii + b1.z; r[7] = a[7] * ii + b1.w;
        if (RELU) {
#pragma unroll
            for (int u = 0; u < 8; ++u) r[u] = fmaxf(r[u], 0.0f) * io;
        }
        if constexpr (sizeof(TO) == 2) {
            __half2 h0 = __float22half2_rn(make_float2(r[0], r[1]));
            __half2 h1 = __float22half2_rn(make_float2(r[2], r[3]));
            __half2 h2 = __float22half2_rn(make_float2(r[4], r[5]));
            __half2 h3 = __float22half2_rn(make_float2(r[6], r[7]));
            uint4 pk;
            pk.x = *(unsigned int*)&h0; pk.y = *(unsigned int*)&h1;
            pk.z = *(unsigned int*)&h2; pk.w = *(unsigned int*)&h3;
            *(uint4*)((__half*)out + (long long)wid * D + colh) = pk;
        } else {
            float* o = (float*)out + (long long)wid * D + colh;
            *(float4*)(o)     = make_float4(r[0], r[1], r[2], r[3]);
            *(float4*)(o + 4) = make_float4(r[4], r[5], r[6], r[7]);
        }
    }
}

// ---------------------------------------------------------------- launch
extern "C" void kernel_launch(void* const* d_in, const int* in_sizes, int n_in,
                              void* d_out, int out_size, void* d_ws, size_t ws_size,
                              hipStream_t stream) {
    const int*   src = (const int*)d_in[0];
    const int*   dst = (const int*)d_in[1];
    const float* x   = (const float*)d_in[2];
    const float* W1  = (const float*)d_in[3];
    const float* b1  = (const float*)d_in[4];
    const float* W2  = (const float*)d_in[5];
    const float* b2  = (const float*)d_in[6];
    float* out = (float*)d_out;

    const int E  = in_sizes[0];
    const int N  = in_sizes[2] / D_IN;
    const int NB = (N + 127) >> 7;                 // 128-node buckets (<= NBMAX)
    const int mean = E / NB;
    const int cap  = mean + mean / 4 + 128;        // generous multinomial margin

    char* ws = (char*)d_ws;
    size_t off = 0;
    auto alloc = [&](size_t bytes) -> void* {
        void* p = ws + off;
        off += (bytes + 255) & ~(size_t)255;
        return p;
    };
    float*          inv_out = (float*)alloc((size_t)N * 4);
    float*          inv_in  = (float*)alloc((size_t)N * 4);
    int*            rowptr  = (int*)alloc((size_t)(N + 1) * 4);
    int*            cntD    = (int*)alloc((size_t)NB * 4);
    int*            cntS    = (int*)alloc((size_t)NB * 4);
    unsigned int*   storeD  = (unsigned int*)alloc((size_t)NB * cap * 4);
    unsigned char*  storeS  = (unsigned char*)alloc((size_t)NB * cap);
    unsigned short* csr_src = (unsigned short*)alloc((size_t)E * 2);
    unsigned short* W1h     = (unsigned short*)alloc(128 * 128 * 2);
    unsigned short* W1l     = (unsigned short*)alloc(128 * 128 * 2);
    unsigned short* W2h     = (unsigned short*)alloc(64 * 128 * 2);
    unsigned short* W2l     = (unsigned short*)alloc(64 * 128 * 2);
    __half*         Y1      = (__half*)alloc((size_t)N * D_HID * 2);
    __half*         H       = (__half*)alloc((size_t)N * D_HID * 2);
    __half*         Y2      = (__half*)alloc((size_t)N * D_OUT * 2);
    (void)ws_size; (void)n_in; (void)out_size;

    const int nbBlk   = (E + CHUNK - 1) / CHUNK;
    const int gemmBlk = (N + 31) / 32;

    // prep (W split + counter zero); sort pass 1 OVERLAPPED with gemm1
    k_prep<<<97, 256, 0, stream>>>(W1, W2, W1h, W1l, W2h, W2l, cntD, cntS, NB);
    k_bucket_gemm<<<nbBlk + gemmBlk, 256, 0, stream>>>(src, dst, E, NB, cap, cntD, cntS,
                                                       storeD, storeS, x, W1h, W1l, Y1, N, nbBlk);
    k_fin<<<2 * NB, 256, 0, stream>>>(storeD, storeS, cntD, cntS, cap, N, NB, E,
                                      rowptr, inv_in, inv_out, csr_src);

    // layer 1 aggregate: H = (half) relu((sum inv_out[s]*Y1[s])*inv_in + b1) * inv_out
    k_gather<D_HID, true, true, __half><<<(N + 3) / 4, 256, 0, stream>>>(
        rowptr, csr_src, Y1, inv_in, inv_out, b1, H, N, inv_out);

    // layer 2: Y2 = H@W2 ; out = gather(Y2)*inv_in + b2
    k_gemm_mfma<D_OUT><<<(N + 31) / 32, 256, 0, stream>>>(H, W2h, W2l, Y2, N);
    k_gather<D_OUT, false, false, float><<<(N + 3) / 4, 256, 0, stream>>>(
        rowptr, csr_src, Y2, inv_in, nullptr, b2, out, N, nullptr);
}

// Round 20
// 129.618 us; speedup vs baseline: 1.1592x; 1.1592x over previous
//
#include <hip/hip_runtime.h>
#include <hip/hip_fp16.h>

#define D_IN  128
#define D_HID 128
#define D_OUT 64
#define NBMAX 512      // max buckets (N <= 65536; packed formats assume this)
#define CHUNK 2048     // edges per k_bucket block
#define FCACHE 3072    // k_fin LDS edge cache (bucket mean ~2046, max ~2300)

typedef __attribute__((ext_vector_type(8))) short bf16x8;
typedef __attribute__((ext_vector_type(4))) float f32x4;

__device__ __forceinline__ unsigned short f2bf_rne(float f) {
    unsigned int u = __float_as_uint(f);
    return (unsigned short)((u + 0x7FFFu + ((u >> 16) & 1u)) >> 16);
}

// ---------------------------------------------------------------- prep:
// split W1/W2 to transposed hi/lo bf16 (B-frag-ready [j][k]) + zero counters.
__launch_bounds__(256)
__global__ void k_prep(const float* __restrict__ W1, const float* __restrict__ W2,
                       unsigned short* __restrict__ W1h, unsigned short* __restrict__ W1l,
                       unsigned short* __restrict__ W2h, unsigned short* __restrict__ W2l,
                       int* __restrict__ cntD, int* __restrict__ cntS, int NB) {
    const int b = blockIdx.x, t = threadIdx.x;
    if (b < 64) {                       // W1: 128x128
        const int i = b * 256 + t;      // i = k*128 + j
        const int k = i >> 7, j = i & 127;
        const float v = W1[i];
        const unsigned short hb = f2bf_rne(v);
        const float hf = __uint_as_float((unsigned int)hb << 16);
        W1h[j * 128 + k] = hb;
        W1l[j * 128 + k] = f2bf_rne(v - hf);
    } else if (b < 96) {                // W2: 128x64
        const int i = (b - 64) * 256 + t;   // i = k*64 + j
        const int k = i >> 6, j = i & 63;
        const float v = W2[i];
        const unsigned short hb = f2bf_rne(v);
        const float hf = __uint_as_float((unsigned int)hb << 16);
        W2h[j * 128 + k] = hb;
        W2l[j * 128 + k] = f2bf_rne(v - hf);
    } else {
        for (int i = t; i < NB; i += 256) { cntD[i] = 0; cntS[i] = 0; }
    }
}

// ---------------------------------------------------------------- merged bucket + gemm1 LDS
struct BucketS {
    int lc[512], ls[512];
    int baD[512], baS[512];
    int gbD[512], gbS[512];
    int wsumD[4], wsumS[4];
    unsigned int  ldsD[CHUNK];
    int           gposD[CHUNK];
    unsigned char ldsS[CHUNK];
    int           gposS[CHUNK];
};
struct GemmS {
    short Ah[32][136];
    short Al[32][136];
};
union SMem { BucketS b; GemmS g; };

// ---- bucket body: counting-sort pass 1, wave-level scans (2 barriers);
// BOTH sides LDS-staged then flushed (write-combining > occupancy — r17 lesson).
__device__ __forceinline__ void bucket_body(
        BucketS& sm, int bx,
        const int* __restrict__ src, const int* __restrict__ dst,
        int E, int NB, int cap,
        int* __restrict__ cntD, int* __restrict__ cntS,
        unsigned int* __restrict__ storeD, unsigned char* __restrict__ storeS) {
    const int t = threadIdx.x;
    const int e0 = bx * CHUNK;
    const int e1 = min(e0 + CHUNK, E);
    const int n  = e1 - e0;

    int sv[8], dv[8];
#pragma unroll
    for (int u = 0; u < 8; ++u) {
        const int i = e0 + u * 256 + t;
        if (i < e1) { sv[u] = src[i]; dv[u] = dst[i]; }
        else        { sv[u] = -1;     dv[u] = -1; }
    }

    sm.lc[t] = 0; sm.lc[t + 256] = 0; sm.ls[t] = 0; sm.ls[t + 256] = 0;
    __syncthreads();
#pragma unroll
    for (int u = 0; u < 8; ++u) {
        if (sv[u] >= 0) {
            atomicAdd(&sm.lc[dv[u] >> 7], 1);
            atomicAdd(&sm.ls[sv[u] >> 7], 1);
        }
    }
    __syncthreads();

    // exclusive scans over 512 bins (thread t owns bins 2t, 2t+1):
    // per-wave shfl scan + cross-wave fixup (2 barriers total)
    const int c0 = sm.lc[2 * t], c1 = sm.lc[2 * t + 1];
    const int s0 = sm.ls[2 * t], s1 = sm.ls[2 * t + 1];
    const int pc = c0 + c1, ps = s0 + s1;
    const int wl = t & 63, wv = t >> 6;
    int incD = pc, incS = ps;
#pragma unroll
    for (int off = 1; off < 64; off <<= 1) {
        const int oD = __shfl_up(incD, off);
        const int oS = __shfl_up(incS, off);
        if (wl >= off) { incD += oD; incS += oS; }
    }
    if (wl == 63) { sm.wsumD[wv] = incD; sm.wsumS[wv] = incS; }
    __syncthreads();
    int baseD = 0, baseS = 0;
#pragma unroll
    for (int ww = 0; ww < 4; ++ww) {
        if (ww < wv) { baseD += sm.wsumD[ww]; baseS += sm.wsumS[ww]; }
    }
    const int exD = baseD + incD - pc;
    const int exS = baseS + incS - ps;
    sm.baD[2 * t] = exD; sm.baD[2 * t + 1] = exD + c0;
    sm.baS[2 * t] = exS; sm.baS[2 * t + 1] = exS + s0;
    __syncthreads();

    for (int i = t; i < NB; i += 256) {
        const int c = sm.lc[i];
        sm.gbD[i] = i * cap + (c ? atomicAdd(&cntD[i], c) : 0);
        const int s = sm.ls[i];
        sm.gbS[i] = i * cap + (s ? atomicAdd(&cntS[i], s) : 0);
    }
    __syncthreads();
    sm.lc[t] = 0; sm.lc[t + 256] = 0; sm.ls[t] = 0; sm.ls[t + 256] = 0;
    __syncthreads();

#pragma unroll
    for (int u = 0; u < 8; ++u) {
        if (sv[u] >= 0) {
            const int s = sv[u], d = dv[u];
            const int bd = d >> 7;
            const int lp = atomicAdd(&sm.lc[bd], 1);
            const int p  = sm.baD[bd] + lp;
            sm.ldsD[p]  = (unsigned int)s | ((unsigned int)(d & 127) << 16);
            sm.gposD[p] = sm.gbD[bd] + lp;
            const int bs = s >> 7;
            const int lq = atomicAdd(&sm.ls[bs], 1);
            const int q  = sm.baS[bs] + lq;
            sm.ldsS[q]  = (unsigned char)(s & 127);
            sm.gposS[q] = sm.gbS[bs] + lq;
        }
    }
    __syncthreads();

    for (int p = t; p < n; p += 256) {
        storeD[sm.gposD[p]] = sm.ldsD[p];
        storeS[sm.gposS[p]] = sm.ldsS[p];
    }
}

// ---- gemm1 body: Y1 = (half)(X @ W1), X fp32, unscaled (scale moved to gather)
__device__ __forceinline__ void gemm1_body(
        GemmS& sm, int bx,
        const float* __restrict__ X,
        const unsigned short* __restrict__ Wth, const unsigned short* __restrict__ Wtl,
        __half* __restrict__ Y, int N) {
    const int t = threadIdx.x;
    const int row0 = bx * 32;

#pragma unroll
    for (int p = 0; p < 4; ++p) {
        const int idx = p * 256 + t;          // float4 units
        const int r   = idx >> 5;
        const int c4  = (idx & 31) << 2;
        const int gr  = row0 + r;
        float4 v = make_float4(0.f, 0.f, 0.f, 0.f);
        if (gr < N) v = *(const float4*)(X + (long long)gr * 128 + c4);
        const float f[4] = {v.x, v.y, v.z, v.w};
        short hh[4], ll[4];
#pragma unroll
        for (int i = 0; i < 4; ++i) {
            const unsigned short hb = f2bf_rne(f[i]);
            const float hf = __uint_as_float(((unsigned int)hb) << 16);
            hh[i] = (short)hb;
            ll[i] = (short)f2bf_rne(f[i] - hf);
        }
        *(short4*)&sm.Ah[r][c4] = make_short4(hh[0], hh[1], hh[2], hh[3]);
        *(short4*)&sm.Al[r][c4] = make_short4(ll[0], ll[1], ll[2], ll[3]);
    }
    __syncthreads();

    constexpr int NT = 4;                     // 128 cols / 32
    const int w    = t >> 6;
    const int lane = t & 63;
    const int rg = w & 1, cg = w >> 1;
    const int lrow = lane & 15;
    const int lk   = (lane >> 4) << 3;
    const int colbase = cg * (16 * NT);

    f32x4 acc[NT];
#pragma unroll
    for (int n = 0; n < NT; ++n) acc[n] = (f32x4){0.f, 0.f, 0.f, 0.f};

#pragma unroll
    for (int ks = 0; ks < 4; ++ks) {
        const int k = ks * 32 + lk;
        const bf16x8 ah = *(const bf16x8*)&sm.Ah[rg * 16 + lrow][k];
        const bf16x8 al = *(const bf16x8*)&sm.Al[rg * 16 + lrow][k];
#pragma unroll
        for (int n = 0; n < NT; ++n) {
            const int col = colbase + n * 16 + lrow;
            const bf16x8 bh = *(const bf16x8*)(Wth + (size_t)col * 128 + k);
            const bf16x8 bl = *(const bf16x8*)(Wtl + (size_t)col * 128 + k);
            acc[n] = __builtin_amdgcn_mfma_f32_16x16x32_bf16(ah, bh, acc[n], 0, 0, 0);
            acc[n] = __builtin_amdgcn_mfma_f32_16x16x32_bf16(ah, bl, acc[n], 0, 0, 0);
            acc[n] = __builtin_amdgcn_mfma_f32_16x16x32_bf16(al, bh, acc[n], 0, 0, 0);
        }
    }

#pragma unroll
    for (int n = 0; n < NT; ++n) {
#pragma unroll
        for (int i = 0; i < 4; ++i) {
            const int r = row0 + rg * 16 + ((lane >> 4) << 2) + i;
            if (r < N)
                Y[(long long)r * D_HID + colbase + n * 16 + lrow] = __float2half(acc[n][i]);
        }
    }
}

// ---- merged dispatch: blocks [0, nbBlk) sort; [nbBlk, nbBlk+gemmBlk) gemm1
__launch_bounds__(256)
__global__ void k_bucket_gemm(const int* __restrict__ src, const int* __restrict__ dst,
                              int E, int NB, int cap,
                              int* __restrict__ cntD, int* __restrict__ cntS,
                              unsigned int* __restrict__ storeD, unsigned char* __restrict__ storeS,
                              const float* __restrict__ X,
                              const unsigned short* __restrict__ Wth,
                              const unsigned short* __restrict__ Wtl,
                              __half* __restrict__ Y, int N, int nbBlk) {
    __shared__ SMem sm;
    const int bx = (int)blockIdx.x;
    if (bx < nbBlk)
        bucket_body(sm.b, bx, src, dst, E, NB, cap, cntD, cntS, storeD, storeS);
    else
        gemm1_body(sm.g, bx - nbBlk, X, Wth, Wtl, Y, N);
}

// ---------------------------------------------------------------- finalize (scan fused)
// Grid = 2*NB: blocks [0,NB) do the dst side (rowptr/inv_in/csr_src);
// blocks [NB,2NB) do the src side (inv_out). Independent -> 2x parallelism.
__launch_bounds__(256)
__global__ void k_fin(const unsigned int* __restrict__ storeD, const unsigned char* __restrict__ storeS,
                      const int* __restrict__ cntD, const int* __restrict__ cntS,
                      int cap, int N, int NB, int E,
                      int* __restrict__ rowptr, float* __restrict__ inv_in,
                      float* __restrict__ inv_out, unsigned short* __restrict__ csr_src) {
    __shared__ int fh[128];
    __shared__ int sc[128];
    __shared__ int cur[128];
    __shared__ int red[256];
    __shared__ unsigned int ecache[FCACHE];
    const int t = threadIdx.x;

    if ((int)blockIdx.x >= NB) {
        // ---- src side: inv_out
        const int b = (int)blockIdx.x - NB;
        const long long sb = (long long)b * cap;
        if (t < 128) fh[t] = 0;
        __syncthreads();
        const int cnts = cntS[b];
        for (int i = t; i < cnts; i += 256) atomicAdd(&fh[storeS[sb + i]], 1);
        __syncthreads();
        if (t < 128) {
            const int node = (b << 7) + t;
            if (node < N) inv_out[node] = rsqrtf((float)max(fh[t], 1));
        }
        return;
    }

    const int b = (int)blockIdx.x;
    const long long sb = (long long)b * cap;

    int partial = 0;
    for (int i = t; i < b; i += 256) partial += cntD[i];
    red[t] = partial;
    __syncthreads();
    for (int off = 128; off > 0; off >>= 1) {
        if (t < off) red[t] += red[t + off];
        __syncthreads();
    }
    const int base = red[0];

    const int cnt = cntD[b];
    const bool cached = (cnt <= FCACHE);
    if (cached) {
        for (int i = t; i < cnt; i += 256) ecache[i] = storeD[sb + i];
    }

    if (t < 128) fh[t] = 0;
    __syncthreads();
    for (int i = t; i < cnt; i += 256) {
        const unsigned int e = cached ? ecache[i] : storeD[sb + i];
        atomicAdd(&fh[e >> 16], 1);
    }
    __syncthreads();
    if (t < 128) sc[t] = fh[t];
    __syncthreads();
    int inc = (t < 128) ? sc[t] : 0;
    for (int off = 1; off < 128; off <<= 1) {
        int o = (t >= off && t < 128) ? sc[t - off] : 0;
        __syncthreads();
        if (t < 128) { inc += o; sc[t] = inc; }
        __syncthreads();
    }
    if (t < 128) {
        const int excl = inc - fh[t];
        cur[t] = excl;
        const int node = (b << 7) + t;
        if (node < N) {
            rowptr[node] = base + excl;
            inv_in[node] = rsqrtf((float)max(fh[t], 1));
        }
    }
    if (b == NB - 1 && t == 128) rowptr[N] = E;
    __syncthreads();
    for (int i = t; i < cnt; i += 256) {
        const unsigned int e = cached ? ecache[i] : storeD[sb + i];
        const int pos = atomicAdd(&cur[e >> 16], 1);
        csr_src[base + pos] = (unsigned short)(e & 0xFFFFu);
    }
}

// ---------------------------------------------------------------- MFMA GEMM (layer 2)
template<int LDN>
__launch_bounds__(256)
__global__ void k_gemm_mfma(const __half* __restrict__ X,
                            const unsigned short* __restrict__ Wth,
                            const unsigned short* __restrict__ Wtl,
                            __half* __restrict__ Y, int N) {
    __shared__ short Ah[32][136], Al[32][136];

    const int t = threadIdx.x;
    const int row0 = blockIdx.x * 32;

#pragma unroll
    for (int p = 0; p < 2; ++p) {
        const int idx = p * 256 + t;          // half8 units
        const int r   = idx >> 4;
        const int c8  = (idx & 15) << 3;
        const int gr  = row0 + r;
        uint4 raw = make_uint4(0u, 0u, 0u, 0u);
        if (gr < N) raw = *(const uint4*)(X + (long long)gr * 128 + c8);
        const __half2* hp = (const __half2*)&raw;
        short hh[8], ll[8];
#pragma unroll
        for (int u = 0; u < 4; ++u) {
            const float2 f2 = __half22float2(hp[u]);
            const float f[2] = {f2.x, f2.y};
#pragma unroll
            for (int q = 0; q < 2; ++q) {
                const unsigned short hb = f2bf_rne(f[q]);
                const float hf = __uint_as_float(((unsigned int)hb) << 16);
                hh[2 * u + q] = (short)hb;
                ll[2 * u + q] = (short)f2bf_rne(f[q] - hf);
            }
        }
        *(short4*)&Ah[r][c8]     = make_short4(hh[0], hh[1], hh[2], hh[3]);
        *(short4*)&Ah[r][c8 + 4] = make_short4(hh[4], hh[5], hh[6], hh[7]);
        *(short4*)&Al[r][c8]     = make_short4(ll[0], ll[1], ll[2], ll[3]);
        *(short4*)&Al[r][c8 + 4] = make_short4(ll[4], ll[5], ll[6], ll[7]);
    }
    __syncthreads();

    constexpr int NT = LDN / 32;
    const int w    = t >> 6;
    const int lane = t & 63;
    const int rg = w & 1, cg = w >> 1;
    const int lrow = lane & 15;
    const int lk   = (lane >> 4) << 3;
    const int colbase = cg * (16 * NT);

    f32x4 acc[NT];
#pragma unroll
    for (int n = 0; n < NT; ++n) acc[n] = (f32x4){0.f, 0.f, 0.f, 0.f};

#pragma unroll
    for (int ks = 0; ks < 4; ++ks) {
        const int k = ks * 32 + lk;
        const bf16x8 ah = *(const bf16x8*)&Ah[rg * 16 + lrow][k];
        const bf16x8 al = *(const bf16x8*)&Al[rg * 16 + lrow][k];
#pragma unroll
        for (int n = 0; n < NT; ++n) {
            const int col = colbase + n * 16 + lrow;
            const bf16x8 bh = *(const bf16x8*)(Wth + (size_t)col * 128 + k);
            const bf16x8 bl = *(const bf16x8*)(Wtl + (size_t)col * 128 + k);
            acc[n] = __builtin_amdgcn_mfma_f32_16x16x32_bf16(ah, bh, acc[n], 0, 0, 0);
            acc[n] = __builtin_amdgcn_mfma_f32_16x16x32_bf16(ah, bl, acc[n], 0, 0, 0);
            acc[n] = __builtin_amdgcn_mfma_f32_16x16x32_bf16(al, bh, acc[n], 0, 0, 0);
        }
    }

#pragma unroll
    for (int n = 0; n < NT; ++n) {
#pragma unroll
        for (int i = 0; i < 4; ++i) {
            const int r = row0 + rg * 16 + ((lane >> 4) << 2) + i;
            if (r < N)
                Y[(long long)r * LDN + colbase + n * 16 + lrow] = __float2half(acc[n][i]);
        }
    }
}

// ---------------------------------------------------------------- CSR gather (fp16 rows, fp32 accum)
// One wave per destination node; 8 halves (16B) per lane; 8-deep MLP unroll.
// SRCSCALE: multiply each source row by inv_src[s] (moves the x*inv_out
// pre-scale of layer 1 into the gather, per-edge).
template<int D, bool RELU, bool SRCSCALE, typename TO>
__launch_bounds__(256)
__global__ void k_gather(const int* __restrict__ rowptr, const unsigned short* __restrict__ csr_src,
                         const __half* __restrict__ Y, const float* __restrict__ inv_in,
                         const float* __restrict__ inv_out, const float* __restrict__ b,
                         TO* __restrict__ out, int N, const float* __restrict__ inv_src) {
    const int wid  = (int)((blockIdx.x * 256u + threadIdx.x) >> 6);
    const int lane = threadIdx.x & 63;
    if (wid >= N) return;

    const int start = rowptr[wid];
    const int end   = rowptr[wid + 1];

    constexpr int LPE = D / 8;            // lanes per edge (16 or 8)
    constexpr int EPW = 64 / LPE;         // edges per group (4 or 8)
    const int grp  = lane / LPE;
    const int colh = (lane % LPE) * 8;

    float a[8];
#pragma unroll
    for (int u = 0; u < 8; ++u) a[u] = 0.0f;

    auto accum = [&](uint4 raw, float io) {
        const __half2* h = (const __half2*)&raw;
#pragma unroll
        for (int u = 0; u < 4; ++u) {
            const float2 f = __half22float2(h[u]);
            if constexpr (SRCSCALE) {
                a[2 * u]     += f.x * io;
                a[2 * u + 1] += f.y * io;
            } else {
                a[2 * u]     += f.x;
                a[2 * u + 1] += f.y;
            }
        }
    };

    for (int k = start; k < end; k += 64) {
        const int idx = k + lane;
        const int sv  = (idx < end) ? (int)csr_src[idx] : 0;
        const int cnt = min(64, end - k);
        int j = 0;
        for (; j + 8 * EPW <= cnt; j += 8 * EPW) {
            int s[8];
#pragma unroll
            for (int u = 0; u < 8; ++u) s[u] = __shfl(sv, j + u * EPW + grp);
            uint4 r[8];
#pragma unroll
            for (int u = 0; u < 8; ++u) r[u] = *(const uint4*)(Y + (long long)s[u] * D + colh);
            float io[8];
            if constexpr (SRCSCALE) {
#pragma unroll
                for (int u = 0; u < 8; ++u) io[u] = inv_src[s[u]];
            }
#pragma unroll
            for (int u = 0; u < 8; ++u) accum(r[u], SRCSCALE ? io[u] : 0.0f);
        }
        for (; j + 4 * EPW <= cnt; j += 4 * EPW) {
            int s[4];
#pragma unroll
            for (int u = 0; u < 4; ++u) s[u] = __shfl(sv, j + u * EPW + grp);
            uint4 r[4];
#pragma unroll
            for (int u = 0; u < 4; ++u) r[u] = *(const uint4*)(Y + (long long)s[u] * D + colh);
            float io[4];
            if constexpr (SRCSCALE) {
#pragma unroll
                for (int u = 0; u < 4; ++u) io[u] = inv_src[s[u]];
            }
#pragma unroll
            for (int u = 0; u < 4; ++u) accum(r[u], SRCSCALE ? io[u] : 0.0f);
        }
        for (; j < cnt; j += EPW) {
            const int jj = j + grp;
            const int s  = __shfl(sv, jj);   // unconditional pull (CDNA divergent-shfl rule)
            if (jj < cnt) {
                const uint4 r = *(const uint4*)(Y + (long long)s * D + colh);
                accum(r, SRCSCALE ? inv_src[s] : 0.0f);
            }
        }
    }

#pragma unroll
    for (int u = 0; u < 8; ++u) a[u] += __shfl_down(a[u], 32);
#pragma unroll
    for (int u = 0; u < 8; ++u) a[u] += __shfl_down(a[u], 16);
    if (EPW == 8) {
#pragma unroll
        for (int u = 0; u < 8; ++u) a[u] += __shfl_down(a[u], 8);
    }

    if (lane < LPE) {
        const float ii = inv_in[wid];
        const float io = RELU ? inv_out[wid] : 0.0f;
        const float4 b0 = *(const float4*)(b + colh);
        const float4 b1 = *(const float4*)(b + colh + 4);
        float r[8];
        r[0] = a[0] * ii + b0.x; r[1] = a[1] * ii + b0.y;
        r[2] = a[2] * ii + b0.z; r[3] = a[3] * ii + b0.w;
        r[4] = a[4] * ii + b1.x; r[5] = a[5] * ii + b1.y;
        r[6] = a[6] * ii + b1.z; r[7] = a[7] * ii + b1.w;
        if (RELU) {
#pragma unroll
            for (int u = 0; u < 8; ++u) r[u] = fmaxf(r[u], 0.0f) * io;
        }
        if constexpr (sizeof(TO) == 2) {
            __half2 h0 = __float22half2_rn(make_float2(r[0], r[1]));
            __half2 h1 = __float22half2_rn(make_float2(r[2], r[3]));
            __half2 h2 = __float22half2_rn(make_float2(r[4], r[5]));
            __half2 h3 = __float22half2_rn(make_float2(r[6], r[7]));
            uint4 pk;
            pk.x = *(unsigned int*)&h0; pk.y = *(unsigned int*)&h1;
            pk.z = *(unsigned int*)&h2; pk.w = *(unsigned int*)&h3;
            *(uint4*)((__half*)out + (long long)wid * D + colh) = pk;
        } else {
            float* o = (float*)out + (long long)wid * D + colh;
            *(float4*)(o)     = make_float4(r[0], r[1], r[2], r[3]);
            *(float4*)(o + 4) = make_float4(r[4], r[5], r[6], r[7]);
        }
    }
}

// ---------------------------------------------------------------- launch
extern "C" void kernel_launch(void* const* d_in, const int* in_sizes, int n_in,
                              void* d_out, int out_size, void* d_ws, size_t ws_size,
                              hipStream_t stream) {
    const int*   src = (const int*)d_in[0];
    const int*   dst = (const int*)d_in[1];
    const float* x   = (const float*)d_in[2];
    const float* W1  = (const float*)d_in[3];
    const float* b1  = (const float*)d_in[4];
    const float* W2  = (const float*)d_in[5];
    const float* b2  = (const float*)d_in[6];
    float* out = (float*)d_out;

    const int E  = in_sizes[0];
    const int N  = in_sizes[2] / D_IN;
    const int NB = (N + 127) >> 7;                 // 128-node buckets (<= NBMAX)
    const int mean = E / NB;
    const int cap  = mean + mean / 4 + 128;        // generous multinomial margin

    char* ws = (char*)d_ws;
    size_t off = 0;
    auto alloc = [&](size_t bytes) -> void* {
        void* p = ws + off;
        off += (bytes + 255) & ~(size_t)255;
        return p;
    };
    float*          inv_out = (float*)alloc((size_t)N * 4);
    float*          inv_in  = (float*)alloc((size_t)N * 4);
    int*            rowptr  = (int*)alloc((size_t)(N + 1) * 4);
    int*            cntD    = (int*)alloc((size_t)NB * 4);
    int*            cntS    = (int*)alloc((size_t)NB * 4);
    unsigned int*   storeD  = (unsigned int*)alloc((size_t)NB * cap * 4);
    unsigned char*  storeS  = (unsigned char*)alloc((size_t)NB * cap);
    unsigned short* csr_src = (unsigned short*)alloc((size_t)E * 2);
    unsigned short* W1h     = (unsigned short*)alloc(128 * 128 * 2);
    unsigned short* W1l     = (unsigned short*)alloc(128 * 128 * 2);
    unsigned short* W2h     = (unsigned short*)alloc(64 * 128 * 2);
    unsigned short* W2l     = (unsigned short*)alloc(64 * 128 * 2);
    __half*         Y1      = (__half*)alloc((size_t)N * D_HID * 2);
    __half*         H       = (__half*)alloc((size_t)N * D_HID * 2);
    __half*         Y2      = (__half*)alloc((size_t)N * D_OUT * 2);
    (void)ws_size; (void)n_in; (void)out_size;

    const int nbBlk   = (E + CHUNK - 1) / CHUNK;
    const int gemmBlk = (N + 31) / 32;

    // prep (W split + counter zero); sort pass 1 OVERLAPPED with gemm1
    k_prep<<<97, 256, 0, stream>>>(W1, W2, W1h, W1l, W2h, W2l, cntD, cntS, NB);
    k_bucket_gemm<<<nbBlk + gemmBlk, 256, 0, stream>>>(src, dst, E, NB, cap, cntD, cntS,
                                                       storeD, storeS, x, W1h, W1l, Y1, N, nbBlk);
    k_fin<<<2 * NB, 256, 0, stream>>>(storeD, storeS, cntD, cntS, cap, N, NB, E,
                                      rowptr, inv_in, inv_out, csr_src);

    // layer 1 aggregate: H = (half) relu((sum inv_out[s]*Y1[s])*inv_in + b1) * inv_out
    k_gather<D_HID, true, true, __half><<<(N + 3) / 4, 256, 0, stream>>>(
        rowptr, csr_src, Y1, inv_in, inv_out, b1, H, N, inv_out);

    // layer 2: Y2 = H@W2 ; out = gather(Y2)*inv_in + b2
    k_gemm_mfma<D_OUT><<<(N + 31) / 32, 256, 0, stream>>>(H, W2h, W2l, Y2, N);
    k_gather<D_OUT, false, false, float><<<(N + 3) / 4, 256, 0, stream>>>(
        rowptr, csr_src, Y2, inv_in, nullptr, b2, out, N, nullptr);
}